// Round 15
// baseline (133.044 us; speedup 1.0000x reference)
//
#include <hip/hip_runtime.h>
#include <cmath>

typedef unsigned short u16;
typedef unsigned int   u32;
typedef __attribute__((ext_vector_type(8))) short short8;
typedef __attribute__((ext_vector_type(4))) float f32x4;

constexpr int BT    = 32;
constexpr int NTOK  = 512;
constexpr int DIM   = 256;
constexpr int HID   = 256;
constexpr int M_ROWS = BT * NTOK;            // 16384
constexpr int HM     = M_ROWS * 32;          // per-head elems in head-major QKV
constexpr size_t TENS = (size_t)M_ROWS * HID; // elems per full tensor
constexpr float LAMBDA_INIT  = 0.35550906759096927f;
constexpr float ONE_MINUS_LI = 0.6444909324090307f;
constexpr float LN_EPS = 1e-5f;
constexpr float QSCALE = 0.36067376022224085f;  // 0.25 * log2(e): fold into Q

// Session lessons:
//  R1: never force tight waves_per_eu (allocator spills).
//  R3: no by-ref-capturing lambdas in hot loops (SROA defeat -> scratch).
//  R4: cross-lane type-punned LDS flows need asm volatile("" ::: "memory").
//  R5: attn P-pipeline latency-neutral. R6/R8: proj staging/tiling neutral.
//  R7: proj not traffic-bound. R9/R11: unexplained correctness failures ->
//      revert-don't-debug. R10: setprio neutral.
//  R12: V-stage rebalance +1.6us -- only WALL-CLOCK-SERIAL waste pays.
//  R13: MFMA rowsum denominators neutral (kept: better absmax, frees VALU).
//  R14: infra failure (container), kernel never ran -- resubmitted verbatim:
//      double-buffered K/V LDS, KCHUNK 128->64 (39.9KB). Compute-then-stage
//      order: staging of chunk c+1 overlaps stragglers' compute of chunk c
//      across waves; one barrier per chunk. K staged by threads 0..127,
//      V by 128..255 (parallel halves).
constexpr int KCHUNK = 64;

#define MFMA16(a, b, c) __builtin_amdgcn_mfma_f32_16x16x32_bf16((a), (b), (c), 0, 0, 0)
#define LDS_FENCE() asm volatile("" ::: "memory")

__device__ __forceinline__ u16 f2bf(float f) {   // RNE
    u32 u = __float_as_uint(f);
    return (u16)((u + 0x7FFFu + ((u >> 16) & 1u)) >> 16);
}

__device__ __forceinline__ float fexp2(float x) {
#if defined(__has_builtin) && __has_builtin(__builtin_amdgcn_exp2f)
    return __builtin_amdgcn_exp2f(x);
#else
    return exp2f(x);
#endif
}

// pack two f32 -> two bf16 (round-half-up) in one dword: a in low half
__device__ __forceinline__ u32 pack_bf16(float a, float b) {
    u32 ua = __float_as_uint(a) + 0x8000u;
    u32 ub = __float_as_uint(b) + 0x8000u;
    return __builtin_amdgcn_perm(ub, ua, 0x07060302u);
}

// ---------------------------------------------------------------------------
// prep_w: transpose + convert W (f32 [k][n]) -> Wt (bf16 [n][k]), 3 matrices
// ---------------------------------------------------------------------------
__global__ __launch_bounds__(256) void prep_w(const float* __restrict__ Wq,
                                              const float* __restrict__ Wk,
                                              const float* __restrict__ Wv,
                                              u16* __restrict__ Wt) {
    const float* W = (blockIdx.z == 0) ? Wq : (blockIdx.z == 1) ? Wk : Wv;
    u16* dst = Wt + (size_t)blockIdx.z * 65536;
    __shared__ float T[64][65];
    const int k0 = blockIdx.x * 64, n0 = blockIdx.y * 64;
    const int tr = threadIdx.x >> 4;
    const int tc = threadIdx.x & 15;
    #pragma unroll
    for (int i = 0; i < 4; ++i) {
        int row = tr + i * 16;
        float4 v = *(const float4*)&W[(size_t)(k0 + row) * HID + n0 + tc * 4];
        T[row][tc * 4 + 0] = v.x; T[row][tc * 4 + 1] = v.y;
        T[row][tc * 4 + 2] = v.z; T[row][tc * 4 + 3] = v.w;
    }
    __syncthreads();
    #pragma unroll
    for (int i = 0; i < 4; ++i) {
        int n = tr + i * 16;
        int k4 = tc * 4;
        uint2 pk;
        pk.x = (u32)f2bf(T[k4 + 0][n]) | ((u32)f2bf(T[k4 + 1][n]) << 16);
        pk.y = (u32)f2bf(T[k4 + 2][n]) | ((u32)f2bf(T[k4 + 3][n]) << 16);
        *(uint2*)&dst[(size_t)(n0 + n) * DIM + k0 + k4] = pk;
    }
}

// ---------------------------------------------------------------------------
// proj: fused QKV GEMM (exact R5/R10-proven structure). Stages x tile
// (f32->bf16 inline), multiplies by all 3 weights. Tile 64x64, BK=64,
// 4 waves each 32x32. Writes head-major bf16 [h][row][32]; Q scaled.
// ---------------------------------------------------------------------------
__global__ __launch_bounds__(256, 3) void proj_kernel(
    const float* __restrict__ x, const u16* __restrict__ Wt,
    u16* __restrict__ Qh, u16* __restrict__ Kh, u16* __restrict__ Vh)
{
    __shared__ u16 As[64 * 72];      // [m][k], stride 72 (144B, 16B aligned)
    __shared__ u16 Bs[3][64 * 72];   // [n][k] per z

    const int tid  = threadIdx.x;
    const int m0   = blockIdx.x * 64;
    const int n0   = blockIdx.y * 64;
    const int lane = tid & 63;
    const int wv   = tid >> 6;
    const int q16  = lane & 15;
    const int quad = lane >> 4;
    const int mw   = (wv >> 1) * 32;
    const int nw   = (wv & 1) * 32;

    const int sr = tid >> 2;          // 0..63 staging row
    const int sc = (tid & 3) * 16;    // 0,16,32,48 (u16 offset within 64-k)

    f32x4 acc[3][4];
    #pragma unroll
    for (int z = 0; z < 3; ++z)
        #pragma unroll
        for (int t = 0; t < 4; ++t)
            acc[z][t] = (f32x4){0.f, 0.f, 0.f, 0.f};

    for (int kk = 0; kk < DIM; kk += 64) {
        // A tile: load f32, convert to bf16
        {
            const float4* xs = (const float4*)&x[(size_t)(m0 + sr) * DIM + kk + sc];
            float4 g0 = xs[0], g1 = xs[1], g2 = xs[2], g3 = xs[3];
            uint4 o0, o1;
            o0.x = (u32)f2bf(g0.x) | ((u32)f2bf(g0.y) << 16);
            o0.y = (u32)f2bf(g0.z) | ((u32)f2bf(g0.w) << 16);
            o0.z = (u32)f2bf(g1.x) | ((u32)f2bf(g1.y) << 16);
            o0.w = (u32)f2bf(g1.z) | ((u32)f2bf(g1.w) << 16);
            o1.x = (u32)f2bf(g2.x) | ((u32)f2bf(g2.y) << 16);
            o1.y = (u32)f2bf(g2.z) | ((u32)f2bf(g2.w) << 16);
            o1.z = (u32)f2bf(g3.x) | ((u32)f2bf(g3.y) << 16);
            o1.w = (u32)f2bf(g3.z) | ((u32)f2bf(g3.w) << 16);
            *(uint4*)&As[sr * 72 + sc]     = o0;
            *(uint4*)&As[sr * 72 + sc + 8] = o1;
        }
        // B tiles (already bf16 in Wt)
        #pragma unroll
        for (int z = 0; z < 3; ++z) {
            const uint4* ws4 = (const uint4*)&Wt[(size_t)z * 65536 + (size_t)(n0 + sr) * DIM + kk + sc];
            *(uint4*)&Bs[z][sr * 72 + sc]     = ws4[0];
            *(uint4*)&Bs[z][sr * 72 + sc + 8] = ws4[1];
        }
        __syncthreads();
        #pragma unroll
        for (int kc = 0; kc < 2; ++kc) {
            short8 a0 = *(const short8*)&As[(mw +      q16) * 72 + kc * 32 + quad * 8];
            short8 a1 = *(const short8*)&As[(mw + 16 + q16) * 72 + kc * 32 + quad * 8];
            #pragma unroll
            for (int z = 0; z < 3; ++z) {
                short8 b0 = *(const short8*)&Bs[z][(nw +      q16) * 72 + kc * 32 + quad * 8];
                short8 b1 = *(const short8*)&Bs[z][(nw + 16 + q16) * 72 + kc * 32 + quad * 8];
                acc[z][0] = MFMA16(a0, b0, acc[z][0]);
                acc[z][1] = MFMA16(a0, b1, acc[z][1]);
                acc[z][2] = MFMA16(a1, b0, acc[z][2]);
                acc[z][3] = MFMA16(a1, b1, acc[z][3]);
            }
        }
        __syncthreads();
    }

    // epilogue: head-major store. C/D: col=lane&15, row=quad*4+reg
    const int hcol = (n0 + nw) >> 5;     // (n0+nw) is a multiple of 32
    #pragma unroll
    for (int z = 0; z < 3; ++z) {
        u16* C = (z == 0) ? Qh : (z == 1) ? Kh : Vh;
        u16* base = C + (size_t)hcol * HM;
        const float s = (z == 0) ? QSCALE : 1.0f;
        #pragma unroll
        for (int r = 0; r < 4; ++r) {
            const int row = m0 + mw + quad * 4 + r;
            base[(size_t)row * 32 + q16]             = f2bf(acc[z][0][r] * s);
            base[(size_t)row * 32 + q16 + 16]        = f2bf(acc[z][1][r] * s);
            base[(size_t)(row + 16) * 32 + q16]      = f2bf(acc[z][2][r] * s);
            base[(size_t)(row + 16) * 32 + q16 + 16] = f2bf(acc[z][3][r] * s);
        }
    }
}

// ---------------------------------------------------------------------------
// attn: transposed-QK MFMA attention + diff combine + LayerNorm.
// R13 compute (MFMA rowsum denominators) + double-buffered K/V LDS with
// KCHUNK=64: iteration c computes chunk c from buf[c&1], then stages chunk
// c+1 into buf[(c+1)&1] (disjoint), then ONE barrier. Fast waves stage while
// slow waves compute. K staged by threads 0..127, V by 128..255.
// LDS 39.9KB.
// ---------------------------------------------------------------------------
__global__ __launch_bounds__(256, 3) void attn_kernel(
    const u16* __restrict__ Qh, const u16* __restrict__ Kh, const u16* __restrict__ Vh,
    const float* __restrict__ lq1, const float* __restrict__ lk1,
    const float* __restrict__ lq2, const float* __restrict__ lk2,
    const float* __restrict__ gamma, const float* __restrict__ beta,
    float* __restrict__ out)
{
    constexpr int VSTR = KCHUNK + 8;         // 72
    constexpr int NKC  = KCHUNK / 32;        // 2 kc steps per chunk
    constexpr int NCH  = NTOK / KCHUNK;      // 8 chunks
    constexpr int KS_ELE = KCHUNK * 40;      // 2560 u16 per K buffer
    constexpr int VT_ELE = 32 * VSTR;        // 2304 u16 per V buffer

    __shared__ u16 Ks[2 * KS_ELE];           // double-buffered [key][dim] 10.0KB
    __shared__ u16 Vts[2 * VT_ELE];          // double-buffered [dim][key]  9.0KB
    __shared__ u16 Pbuf[4][2][2][16 * 40];   // [wave][parity][matrix][q][key] 20.5KB

    const int qh  = blockIdx.x;   // 0..3 (128 q rows each)
    const int h   = blockIdx.y;   // 0..7
    const int bt  = blockIdx.z;   // 0..31
    const int tid = threadIdx.x;
    const int lane = tid & 63;
    const int wv   = tid >> 6;
    const int q16  = lane & 15;
    const int quad = lane >> 4;

    // lambda scalar (uniform path)
    float sa = 0.f, sb = 0.f;
    #pragma unroll
    for (int d = 0; d < 16; ++d) { sa += lq1[d] * lk1[d]; sb += lq2[d] * lk2[d]; }
    const float lam = __expf(sa) - __expf(sb) + LAMBDA_INIT;

    // Q B-fragments for this wave's two 16-row q blocks (pre-scaled at proj)
    short8 qv[2];
    #pragma unroll
    for (int qbi = 0; qbi < 2; ++qbi) {
        const int qrow = bt * NTOK + qh * 128 + (qbi * 4 + wv) * 16 + q16;
        qv[qbi] = *(const short8*)(Qh + (size_t)h * HM + (size_t)qrow * 32 + quad * 8);
    }

    const short8 z8 = {0, 0, 0, 0, 0, 0, 0, 0};
    const f32x4  z4 = {0.f, 0.f, 0.f, 0.f};
    const short8 ones8 = {(short)0x3F80, (short)0x3F80, (short)0x3F80, (short)0x3F80,
                          (short)0x3F80, (short)0x3F80, (short)0x3F80, (short)0x3F80};

    f32x4 o1lo[2], o1hi[2], o2lo[2], o2hi[2];
    f32x4 accl1[2], accl2[2];            // rowsum accumulators (denominators)
    #pragma unroll
    for (int qbi = 0; qbi < 2; ++qbi) {
        o1lo[qbi] = z4; o1hi[qbi] = z4; o2lo[qbi] = z4; o2hi[qbi] = z4;
        accl1[qbi] = z4; accl2[qbi] = z4;
    }

    const u16* Kbase = Kh + (size_t)h * HM + (size_t)(bt * NTOK) * 32;
    const u16* Vbase = Vh + (size_t)h * HM + (size_t)(bt * NTOK) * 32;

    // -------- prologue: stage chunk 0 into buffer 0 --------
    if (tid < 128) {
        const int key  = tid >> 1;
        const int half = (tid & 1) * 16;
        const uint4* src = (const uint4*)(Kbase + (size_t)key * 32 + half);
        uint4* dst = (uint4*)&Ks[key * 40 + half];
        dst[0] = src[0]; dst[1] = src[1];
    } else {
        const int vt = tid - 128;
        const int pr = vt >> 2;           // key pair 0..31
        const int qd = vt & 3;            // dword quarter 0..3
        const int j0 = pr * 2;
        const u16* v0 = Vbase + (size_t)j0 * 32;
        union U { uint4 q4; u32 w[4]; } ra, rb;
        ra.q4 = ((const uint4*)v0)[qd];
        rb.q4 = ((const uint4*)(v0 + 32))[qd];
        #pragma unroll
        for (int k = 0; k < 4; ++k) {
            const int w = qd * 4 + k;
            u32 lo = __builtin_amdgcn_perm(rb.w[k], ra.w[k], 0x05040100u);
            u32 hi = __builtin_amdgcn_perm(rb.w[k], ra.w[k], 0x07060302u);
            *(u32*)&Vts[(2 * w)     * VSTR + j0] = lo;
            *(u32*)&Vts[(2 * w + 1) * VSTR + j0] = hi;
        }
    }
    __syncthreads();

    for (int chunk = 0; chunk < NCH; ++chunk) {
        const int cb = chunk & 1;
        const u16* ksb = &Ks[cb * KS_ELE];
        const u16* vtb = &Vts[cb * VT_ELE];

        // ---- compute chunk from buf[cb] ----
        #pragma unroll
        for (int qbi = 0; qbi < 2; ++qbi) {
            const short8 A1 = (lane < 32) ? qv[qbi] : z8;  // dims 0..15
            const short8 A2 = (lane < 32) ? z8 : qv[qbi];  // dims 16..31

            #pragma unroll
            for (int kc = 0; kc < NKC; ++kc) {
                // ---- QK phase for step kc -> Pbuf[wv][kc&1] ----
                #pragma unroll
                for (int sub = 0; sub < 2; ++sub) {
                    const int key0 = kc * 32 + sub * 16;
                    short8 kf = *(const short8*)&ksb[(key0 + q16) * 40 + quad * 8];
                    // S^T: D[key=quad*4+r][q=q16]
                    __builtin_amdgcn_s_setprio(1);
                    f32x4 s1 = MFMA16(kf, A1, z4);
                    f32x4 s2 = MFMA16(kf, A2, z4);
                    __builtin_amdgcn_s_setprio(0);
                    float p0 = fexp2(s1[0]), p1 = fexp2(s1[1]);
                    float p2 = fexp2(s1[2]), p3 = fexp2(s1[3]);
                    uint2 w1; w1.x = pack_bf16(p0, p1); w1.y = pack_bf16(p2, p3);
                    *(uint2*)&Pbuf[wv][kc & 1][0][q16 * 40 + sub * 16 + quad * 4] = w1;
                    float r0 = fexp2(s2[0]), r1 = fexp2(s2[1]);
                    float r2 = fexp2(s2[2]), r3 = fexp2(s2[3]);
                    uint2 w2; w2.x = pack_bf16(r0, r1); w2.y = pack_bf16(r2, r3);
                    *(uint2*)&Pbuf[wv][kc & 1][1][q16 * 40 + sub * 16 + quad * 4] = w2;
                }
                LDS_FENCE();   // pin: QK writes of kc stay above PV reads below
                // ---- PV phase for step kc-1 <- Pbuf[wv][(kc-1)&1] ----
                if (kc > 0) {
                    const int pk = kc - 1;
                    const int pb = (kc - 1) & 1;
                    short8 pf1 = *(const short8*)&Pbuf[wv][pb][0][q16 * 40 + quad * 8];
                    short8 pf2 = *(const short8*)&Pbuf[wv][pb][1][q16 * 40 + quad * 8];
                    short8 vlo = *(const short8*)&vtb[q16        * VSTR + pk * 32 + quad * 8];
                    short8 vhi = *(const short8*)&vtb[(16 + q16) * VSTR + pk * 32 + quad * 8];
                    __builtin_amdgcn_s_setprio(1);
                    o1lo[qbi] = MFMA16(pf1, vlo, o1lo[qbi]);
                    o1hi[qbi] = MFMA16(pf1, vhi, o1hi[qbi]);
                    o2lo[qbi] = MFMA16(pf2, vlo, o2lo[qbi]);
                    o2hi[qbi] = MFMA16(pf2, vhi, o2hi[qbi]);
                    accl1[qbi] = MFMA16(pf1, ones8, accl1[qbi]);
                    accl2[qbi] = MFMA16(pf2, ones8, accl2[qbi]);
                    __builtin_amdgcn_s_setprio(0);
                }
                LDS_FENCE();   // pin: PV reads of kc-1 stay above QK writes of kc+1
            }
            // ---- PV tail for step NKC-1 ----
            {
                const int pk = NKC - 1;
                const int pb = (NKC - 1) & 1;
                short8 pf1 = *(const short8*)&Pbuf[wv][pb][0][q16 * 40 + quad * 8];
                short8 pf2 = *(const short8*)&Pbuf[wv][pb][1][q16 * 40 + quad * 8];
                short8 vlo = *(const short8*)&vtb[q16        * VSTR + pk * 32 + quad * 8];
                short8 vhi = *(const short8*)&vtb[(16 + q16) * VSTR + pk * 32 + quad * 8];
                __builtin_amdgcn_s_setprio(1);
                o1lo[qbi] = MFMA16(pf1, vlo, o1lo[qbi]);
                o1hi[qbi] = MFMA16(pf1, vhi, o1hi[qbi]);
                o2lo[qbi] = MFMA16(pf2, vlo, o2lo[qbi]);
                o2hi[qbi] = MFMA16(pf2, vhi, o2hi[qbi]);
                accl1[qbi] = MFMA16(pf1, ones8, accl1[qbi]);
                accl2[qbi] = MFMA16(pf2, ones8, accl2[qbi]);
                __builtin_amdgcn_s_setprio(0);
            }
            LDS_FENCE();       // pin: tail reads stay above next qbi's QK writes
        }

        // ---- stage chunk+1 into buf[cb^1] (disjoint from buf[cb] above) ----
        if (chunk < NCH - 1) {
            const size_t coff = (size_t)(chunk + 1) * KCHUNK * 32;
            if (tid < 128) {
                const int key  = tid >> 1;
                const int half = (tid & 1) * 16;
                const uint4* src = (const uint4*)(Kbase + coff + (size_t)key * 32 + half);
                uint4* dst = (uint4*)&Ks[(cb ^ 1) * KS_ELE + key * 40 + half];
                dst[0] = src[0]; dst[1] = src[1];
            } else {
                const int vt = tid - 128;
                const int pr = vt >> 2;
                const int qd = vt & 3;
                const int j0 = pr * 2;
                const u16* v0 = Vbase + coff + (size_t)j0 * 32;
                union U { uint4 q4; u32 w[4]; } ra, rb;
                ra.q4 = ((const uint4*)v0)[qd];
                rb.q4 = ((const uint4*)(v0 + 32))[qd];
                #pragma unroll
                for (int k = 0; k < 4; ++k) {
                    const int w = qd * 4 + k;
                    u32 lo = __builtin_amdgcn_perm(rb.w[k], ra.w[k], 0x05040100u);
                    u32 hi = __builtin_amdgcn_perm(rb.w[k], ra.w[k], 0x07060302u);
                    *(u32*)&Vts[(cb ^ 1) * VT_ELE + (2 * w)     * VSTR + j0] = lo;
                    *(u32*)&Vts[(cb ^ 1) * VT_ELE + (2 * w + 1) * VSTR + j0] = hi;
                }
            }
        }
        __syncthreads();   // one barrier per chunk: staging done + compute done
    }

    // ---- epilogue: normalize (denominators row-aligned), diff combine,
    //      LayerNorm(32), store ----
    const float g_lo = gamma[q16],      g_hi = gamma[16 + q16];
    const float b_lo = beta[q16],       b_hi = beta[16 + q16];

    #pragma unroll
    for (int qbi = 0; qbi < 2; ++qbi) {
        #pragma unroll
        for (int r = 0; r < 4; ++r) {
            const float i1 = 1.0f / accl1[qbi][r];   // rowsum for q=(lane>>4)*4+r
            const float i2 = 1.0f / accl2[qbi][r];
            const float ylo = o1lo[qbi][r] * i1 - lam * (o2lo[qbi][r] * i2);
            const float yhi = o1hi[qbi][r] * i1 - lam * (o2hi[qbi][r] * i2);

            float s  = ylo + yhi;
            float s2 = ylo * ylo + yhi * yhi;
            #pragma unroll
            for (int off = 1; off < 16; off <<= 1) {
                s  += __shfl_xor(s,  off);
                s2 += __shfl_xor(s2, off);
            }
            const float mu   = s * (1.0f / 32.0f);
            const float var  = s2 * (1.0f / 32.0f) - mu * mu;
            const float rstd = rsqrtf(var + LN_EPS);

            const int row = bt * NTOK + qh * 128 + (qbi * 4 + wv) * 16 + quad * 4 + r;
            float* orow = out + (size_t)row * HID + h * 32;
            orow[q16]      = ((ylo - mu) * rstd * g_lo + b_lo) * ONE_MINUS_LI;
            orow[16 + q16] = ((yhi - mu) * rstd * g_hi + b_hi) * ONE_MINUS_LI;
        }
    }
}

// ---------------------------------------------------------------------------
extern "C" void kernel_launch(void* const* d_in, const int* in_sizes, int n_in,
                              void* d_out, int out_size, void* d_ws, size_t ws_size,
                              hipStream_t stream) {
    const float* x   = (const float*)d_in[0];
    const float* Wq  = (const float*)d_in[1];
    const float* Wk  = (const float*)d_in[2];
    const float* Wv  = (const float*)d_in[3];
    const float* lq1 = (const float*)d_in[4];
    const float* lk1 = (const float*)d_in[5];
    const float* lq2 = (const float*)d_in[6];
    const float* lk2 = (const float*)d_in[7];
    const float* gam = (const float*)d_in[8];
    const float* bet = (const float*)d_in[9];
    float* out = (float*)d_out;

    u16* ws = (u16*)d_ws;
    u16* Wt = ws;                 // 3 * 65536
    u16* Qh = Wt + 3 * 65536;     // head-major [8][16384][32]
    u16* Kh = Qh + TENS;
    u16* Vh = Kh + TENS;

    hipLaunchKernelGGL(prep_w, dim3(4, 4, 3), dim3(256), 0, stream, Wq, Wk, Wv, Wt);
    hipLaunchKernelGGL(proj_kernel, dim3(M_ROWS / 64, HID / 64), dim3(256), 0, stream,
                       x, Wt, Qh, Kh, Vh);
    hipLaunchKernelGGL(attn_kernel, dim3(4, 8, 32), dim3(256), 0, stream,
                       Qh, Kh, Vh, lq1, lk1, lq2, lk2, gam, bet, out);
}

// Round 16
// 131.268 us; speedup vs baseline: 1.0135x; 1.0135x over previous
//
#include <hip/hip_runtime.h>
#include <cmath>

typedef unsigned short u16;
typedef unsigned int   u32;
typedef __attribute__((ext_vector_type(8))) short short8;
typedef __attribute__((ext_vector_type(4))) float f32x4;

constexpr int BT    = 32;
constexpr int NTOK  = 512;
constexpr int DIM   = 256;
constexpr int HID   = 256;
constexpr int M_ROWS = BT * NTOK;            // 16384
constexpr int HM     = M_ROWS * 32;          // per-head elems in head-major QKV
constexpr size_t TENS = (size_t)M_ROWS * HID; // elems per full tensor
constexpr float LAMBDA_INIT  = 0.35550906759096927f;
constexpr float ONE_MINUS_LI = 0.6444909324090307f;
constexpr float LN_EPS = 1e-5f;
constexpr float QSCALE = 0.36067376022224085f;  // 0.25 * log2(e): fold into Q

// Session lessons:
//  R1: never force tight waves_per_eu (allocator spills).
//  R3: no by-ref-capturing lambdas in hot loops (SROA defeat -> scratch).
//  R4: cross-lane type-punned LDS flows need asm volatile("" ::: "memory").
//  R5/R9/R15: attn staging latency family (exposed / reg-prefetch / LDS
//      double-buffer) all neutral-to-negative -> falsified.
//  R6/R7/R8: proj staging/traffic/tiling all neutral.
//  R10: setprio neutral. R11: LDS-bounce epilogue failed harness check.
//  R12: V-stage rebalance +1.6us -- only WALL-CLOCK-SERIAL waste pays.
//  R13: MFMA rowsum denominators neutral (kept: best absmax, frees VALU).
//  R16 (this): base = exact R13 (best-known). ONE change: XCD-aware
//      swizzle of attn block mapping so the 4 qh-siblings of each (h,bt)
//      share id%8 (same XCD under round-robin) -> K/V fetched once into
//      that XCD's L2 instead of 4 cross-XCD HBM fetches (FETCH 37MB vs
//      25MB unique).
constexpr int KCHUNK = 128;

#define MFMA16(a, b, c) __builtin_amdgcn_mfma_f32_16x16x32_bf16((a), (b), (c), 0, 0, 0)
#define LDS_FENCE() asm volatile("" ::: "memory")

__device__ __forceinline__ u16 f2bf(float f) {   // RNE
    u32 u = __float_as_uint(f);
    return (u16)((u + 0x7FFFu + ((u >> 16) & 1u)) >> 16);
}

__device__ __forceinline__ float fexp2(float x) {
#if defined(__has_builtin) && __has_builtin(__builtin_amdgcn_exp2f)
    return __builtin_amdgcn_exp2f(x);
#else
    return exp2f(x);
#endif
}

// pack two f32 -> two bf16 (round-half-up) in one dword: a in low half
__device__ __forceinline__ u32 pack_bf16(float a, float b) {
    u32 ua = __float_as_uint(a) + 0x8000u;
    u32 ub = __float_as_uint(b) + 0x8000u;
    return __builtin_amdgcn_perm(ub, ua, 0x07060302u);
}

// ---------------------------------------------------------------------------
// prep_w: transpose + convert W (f32 [k][n]) -> Wt (bf16 [n][k]), 3 matrices
// ---------------------------------------------------------------------------
__global__ __launch_bounds__(256) void prep_w(const float* __restrict__ Wq,
                                              const float* __restrict__ Wk,
                                              const float* __restrict__ Wv,
                                              u16* __restrict__ Wt) {
    const float* W = (blockIdx.z == 0) ? Wq : (blockIdx.z == 1) ? Wk : Wv;
    u16* dst = Wt + (size_t)blockIdx.z * 65536;
    __shared__ float T[64][65];
    const int k0 = blockIdx.x * 64, n0 = blockIdx.y * 64;
    const int tr = threadIdx.x >> 4;
    const int tc = threadIdx.x & 15;
    #pragma unroll
    for (int i = 0; i < 4; ++i) {
        int row = tr + i * 16;
        float4 v = *(const float4*)&W[(size_t)(k0 + row) * HID + n0 + tc * 4];
        T[row][tc * 4 + 0] = v.x; T[row][tc * 4 + 1] = v.y;
        T[row][tc * 4 + 2] = v.z; T[row][tc * 4 + 3] = v.w;
    }
    __syncthreads();
    #pragma unroll
    for (int i = 0; i < 4; ++i) {
        int n = tr + i * 16;
        int k4 = tc * 4;
        uint2 pk;
        pk.x = (u32)f2bf(T[k4 + 0][n]) | ((u32)f2bf(T[k4 + 1][n]) << 16);
        pk.y = (u32)f2bf(T[k4 + 2][n]) | ((u32)f2bf(T[k4 + 3][n]) << 16);
        *(uint2*)&dst[(size_t)(n0 + n) * DIM + k0 + k4] = pk;
    }
}

// ---------------------------------------------------------------------------
// proj: fused QKV GEMM (exact R5/R10-proven structure). Stages x tile
// (f32->bf16 inline), multiplies by all 3 weights. Tile 64x64, BK=64,
// 4 waves each 32x32. Writes head-major bf16 [h][row][32]; Q scaled.
// ---------------------------------------------------------------------------
__global__ __launch_bounds__(256, 3) void proj_kernel(
    const float* __restrict__ x, const u16* __restrict__ Wt,
    u16* __restrict__ Qh, u16* __restrict__ Kh, u16* __restrict__ Vh)
{
    __shared__ u16 As[64 * 72];      // [m][k], stride 72 (144B, 16B aligned)
    __shared__ u16 Bs[3][64 * 72];   // [n][k] per z

    const int tid  = threadIdx.x;
    const int m0   = blockIdx.x * 64;
    const int n0   = blockIdx.y * 64;
    const int lane = tid & 63;
    const int wv   = tid >> 6;
    const int q16  = lane & 15;
    const int quad = lane >> 4;
    const int mw   = (wv >> 1) * 32;
    const int nw   = (wv & 1) * 32;

    const int sr = tid >> 2;          // 0..63 staging row
    const int sc = (tid & 3) * 16;    // 0,16,32,48 (u16 offset within 64-k)

    f32x4 acc[3][4];
    #pragma unroll
    for (int z = 0; z < 3; ++z)
        #pragma unroll
        for (int t = 0; t < 4; ++t)
            acc[z][t] = (f32x4){0.f, 0.f, 0.f, 0.f};

    for (int kk = 0; kk < DIM; kk += 64) {
        // A tile: load f32, convert to bf16
        {
            const float4* xs = (const float4*)&x[(size_t)(m0 + sr) * DIM + kk + sc];
            float4 g0 = xs[0], g1 = xs[1], g2 = xs[2], g3 = xs[3];
            uint4 o0, o1;
            o0.x = (u32)f2bf(g0.x) | ((u32)f2bf(g0.y) << 16);
            o0.y = (u32)f2bf(g0.z) | ((u32)f2bf(g0.w) << 16);
            o0.z = (u32)f2bf(g1.x) | ((u32)f2bf(g1.y) << 16);
            o0.w = (u32)f2bf(g1.z) | ((u32)f2bf(g1.w) << 16);
            o1.x = (u32)f2bf(g2.x) | ((u32)f2bf(g2.y) << 16);
            o1.y = (u32)f2bf(g2.z) | ((u32)f2bf(g2.w) << 16);
            o1.z = (u32)f2bf(g3.x) | ((u32)f2bf(g3.y) << 16);
            o1.w = (u32)f2bf(g3.z) | ((u32)f2bf(g3.w) << 16);
            *(uint4*)&As[sr * 72 + sc]     = o0;
            *(uint4*)&As[sr * 72 + sc + 8] = o1;
        }
        // B tiles (already bf16 in Wt)
        #pragma unroll
        for (int z = 0; z < 3; ++z) {
            const uint4* ws4 = (const uint4*)&Wt[(size_t)z * 65536 + (size_t)(n0 + sr) * DIM + kk + sc];
            *(uint4*)&Bs[z][sr * 72 + sc]     = ws4[0];
            *(uint4*)&Bs[z][sr * 72 + sc + 8] = ws4[1];
        }
        __syncthreads();
        #pragma unroll
        for (int kc = 0; kc < 2; ++kc) {
            short8 a0 = *(const short8*)&As[(mw +      q16) * 72 + kc * 32 + quad * 8];
            short8 a1 = *(const short8*)&As[(mw + 16 + q16) * 72 + kc * 32 + quad * 8];
            #pragma unroll
            for (int z = 0; z < 3; ++z) {
                short8 b0 = *(const short8*)&Bs[z][(nw +      q16) * 72 + kc * 32 + quad * 8];
                short8 b1 = *(const short8*)&Bs[z][(nw + 16 + q16) * 72 + kc * 32 + quad * 8];
                acc[z][0] = MFMA16(a0, b0, acc[z][0]);
                acc[z][1] = MFMA16(a0, b1, acc[z][1]);
                acc[z][2] = MFMA16(a1, b0, acc[z][2]);
                acc[z][3] = MFMA16(a1, b1, acc[z][3]);
            }
        }
        __syncthreads();
    }

    // epilogue: head-major store. C/D: col=lane&15, row=quad*4+reg
    const int hcol = (n0 + nw) >> 5;     // (n0+nw) is a multiple of 32
    #pragma unroll
    for (int z = 0; z < 3; ++z) {
        u16* C = (z == 0) ? Qh : (z == 1) ? Kh : Vh;
        u16* base = C + (size_t)hcol * HM;
        const float s = (z == 0) ? QSCALE : 1.0f;
        #pragma unroll
        for (int r = 0; r < 4; ++r) {
            const int row = m0 + mw + quad * 4 + r;
            base[(size_t)row * 32 + q16]             = f2bf(acc[z][0][r] * s);
            base[(size_t)row * 32 + q16 + 16]        = f2bf(acc[z][1][r] * s);
            base[(size_t)(row + 16) * 32 + q16]      = f2bf(acc[z][2][r] * s);
            base[(size_t)(row + 16) * 32 + q16 + 16] = f2bf(acc[z][3][r] * s);
        }
    }
}

// ---------------------------------------------------------------------------
// attn: transposed-QK MFMA attention + diff combine + LayerNorm.
// Exact R13 compute (KCHUNK=128 single-buffer, MFMA rowsum denominators,
// 256-thread V-stage, setprio). ONE change: 1-D grid with XCD-aware
// swizzle -- the 4 qh-siblings of each (h,bt) get ids congruent mod 8,
// landing on the same XCD so K/V is fetched into one L2 and shared.
//   id: r=id&7, qh=(id>>3)&3, p=(id>>5)*8+r, h=p&7, bt=p>>3  (bijective)
// ---------------------------------------------------------------------------
__global__ __launch_bounds__(256, 3) void attn_kernel(
    const u16* __restrict__ Qh, const u16* __restrict__ Kh, const u16* __restrict__ Vh,
    const float* __restrict__ lq1, const float* __restrict__ lk1,
    const float* __restrict__ lq2, const float* __restrict__ lk2,
    const float* __restrict__ gamma, const float* __restrict__ beta,
    float* __restrict__ out)
{
    constexpr int VSTR = KCHUNK + 8;
    constexpr int NKC  = KCHUNK / 32;        // 4 kc steps per chunk

    __shared__ u16 Ks[KCHUNK * 40];          // [key][dim] 10.0KB
    __shared__ u16 Vts[32 * VSTR];           // [dim][key]  8.5KB
    __shared__ u16 Pbuf[4][2][2][16 * 40];   // [wave][parity][matrix][q][key] 20.5KB

    // XCD-aware swizzled block mapping (see header comment)
    const int id  = blockIdx.x;
    const int rr  = id & 7;
    const int qh  = (id >> 3) & 3;            // 0..3 (128 q rows each)
    const int p   = (id >> 5) * 8 + rr;       // pair index 0..255
    const int h   = p & 7;                    // 0..7
    const int bt  = p >> 3;                   // 0..31

    const int tid = threadIdx.x;
    const int lane = tid & 63;
    const int wv   = tid >> 6;
    const int q16  = lane & 15;
    const int quad = lane >> 4;

    // lambda scalar (uniform path)
    float sa = 0.f, sb = 0.f;
    #pragma unroll
    for (int d = 0; d < 16; ++d) { sa += lq1[d] * lk1[d]; sb += lq2[d] * lk2[d]; }
    const float lam = __expf(sa) - __expf(sb) + LAMBDA_INIT;

    // Q B-fragments for this wave's two 16-row q blocks (pre-scaled at proj)
    short8 qv[2];
    #pragma unroll
    for (int qbi = 0; qbi < 2; ++qbi) {
        const int qrow = bt * NTOK + qh * 128 + (qbi * 4 + wv) * 16 + q16;
        qv[qbi] = *(const short8*)(Qh + (size_t)h * HM + (size_t)qrow * 32 + quad * 8);
    }

    const short8 z8 = {0, 0, 0, 0, 0, 0, 0, 0};
    const f32x4  z4 = {0.f, 0.f, 0.f, 0.f};
    const short8 ones8 = {(short)0x3F80, (short)0x3F80, (short)0x3F80, (short)0x3F80,
                          (short)0x3F80, (short)0x3F80, (short)0x3F80, (short)0x3F80};

    f32x4 o1lo[2], o1hi[2], o2lo[2], o2hi[2];
    f32x4 accl1[2], accl2[2];            // rowsum accumulators (denominators)
    #pragma unroll
    for (int qbi = 0; qbi < 2; ++qbi) {
        o1lo[qbi] = z4; o1hi[qbi] = z4; o2lo[qbi] = z4; o2hi[qbi] = z4;
        accl1[qbi] = z4; accl2[qbi] = z4;
    }

    for (int chunk = 0; chunk < NTOK / KCHUNK; ++chunk) {
        if (chunk) __syncthreads();   // drain previous chunk's LDS reads
        // ---- stage K chunk: 128 rows, 2 threads per row (32B each, coalesced) ----
        {
            const int key  = tid >> 1;
            const int half = (tid & 1) * 16;   // u16 offset within 32-dim row
            const uint4* src = (const uint4*)(Kh + (size_t)h * HM +
                                (size_t)(bt * NTOK + chunk * KCHUNK + key) * 32 + half);
            uint4* dst = (uint4*)&Ks[key * 40 + half];
            dst[0] = src[0]; dst[1] = src[1];
        }
        // ---- stage V chunk transposed: ALL 256 threads (R12 rebalance) ----
        {
            const int pr = tid >> 2;          // key pair 0..63
            const int qd = tid & 3;           // dword quarter 0..3
            const int j0 = pr * 2;
            const u16* v0 = Vh + (size_t)h * HM + (size_t)(bt * NTOK + chunk * KCHUNK + j0) * 32;
            union U { uint4 q4; u32 w[4]; } ra, rb;
            ra.q4 = ((const uint4*)v0)[qd];        // key j0,  dims 8qd..8qd+7
            rb.q4 = ((const uint4*)(v0 + 32))[qd]; // key j0+1, same dims
            #pragma unroll
            for (int k = 0; k < 4; ++k) {
                const int w = qd * 4 + k;          // dword index 0..15 (dims 2w,2w+1)
                u32 lo = __builtin_amdgcn_perm(rb.w[k], ra.w[k], 0x05040100u); // dim 2w
                u32 hi = __builtin_amdgcn_perm(rb.w[k], ra.w[k], 0x07060302u); // dim 2w+1
                *(u32*)&Vts[(2 * w)     * VSTR + j0] = lo;
                *(u32*)&Vts[(2 * w + 1) * VSTR + j0] = hi;
            }
        }
        __syncthreads();

        #pragma unroll
        for (int qbi = 0; qbi < 2; ++qbi) {
            const short8 A1 = (lane < 32) ? qv[qbi] : z8;  // dims 0..15
            const short8 A2 = (lane < 32) ? z8 : qv[qbi];  // dims 16..31

            #pragma unroll
            for (int kc = 0; kc < NKC; ++kc) {
                // ---- QK phase for step kc -> Pbuf[wv][kc&1] ----
                #pragma unroll
                for (int sub = 0; sub < 2; ++sub) {
                    const int key0 = kc * 32 + sub * 16;
                    short8 kf = *(const short8*)&Ks[(key0 + q16) * 40 + quad * 8];
                    // S^T: D[key=quad*4+r][q=q16]
                    __builtin_amdgcn_s_setprio(1);
                    f32x4 s1 = MFMA16(kf, A1, z4);
                    f32x4 s2 = MFMA16(kf, A2, z4);
                    __builtin_amdgcn_s_setprio(0);
                    float p0 = fexp2(s1[0]), p1 = fexp2(s1[1]);
                    float p2 = fexp2(s1[2]), p3 = fexp2(s1[3]);
                    uint2 w1; w1.x = pack_bf16(p0, p1); w1.y = pack_bf16(p2, p3);
                    *(uint2*)&Pbuf[wv][kc & 1][0][q16 * 40 + sub * 16 + quad * 4] = w1;
                    float r0 = fexp2(s2[0]), r1 = fexp2(s2[1]);
                    float r2 = fexp2(s2[2]), r3 = fexp2(s2[3]);
                    uint2 w2; w2.x = pack_bf16(r0, r1); w2.y = pack_bf16(r2, r3);
                    *(uint2*)&Pbuf[wv][kc & 1][1][q16 * 40 + sub * 16 + quad * 4] = w2;
                }
                LDS_FENCE();   // pin: QK writes of kc stay above PV reads below
                // ---- PV phase for step kc-1 <- Pbuf[wv][(kc-1)&1] ----
                if (kc > 0) {
                    const int pk = kc - 1;
                    const int pb = (kc - 1) & 1;
                    short8 pf1 = *(const short8*)&Pbuf[wv][pb][0][q16 * 40 + quad * 8];
                    short8 pf2 = *(const short8*)&Pbuf[wv][pb][1][q16 * 40 + quad * 8];
                    short8 vlo = *(const short8*)&Vts[q16        * VSTR + pk * 32 + quad * 8];
                    short8 vhi = *(const short8*)&Vts[(16 + q16) * VSTR + pk * 32 + quad * 8];
                    __builtin_amdgcn_s_setprio(1);
                    o1lo[qbi] = MFMA16(pf1, vlo, o1lo[qbi]);
                    o1hi[qbi] = MFMA16(pf1, vhi, o1hi[qbi]);
                    o2lo[qbi] = MFMA16(pf2, vlo, o2lo[qbi]);
                    o2hi[qbi] = MFMA16(pf2, vhi, o2hi[qbi]);
                    accl1[qbi] = MFMA16(pf1, ones8, accl1[qbi]);
                    accl2[qbi] = MFMA16(pf2, ones8, accl2[qbi]);
                    __builtin_amdgcn_s_setprio(0);
                }
                LDS_FENCE();   // pin: PV reads of kc-1 stay above QK writes of kc+1
            }
            // ---- PV tail for step NKC-1 ----
            {
                const int pk = NKC - 1;
                const int pb = (NKC - 1) & 1;
                short8 pf1 = *(const short8*)&Pbuf[wv][pb][0][q16 * 40 + quad * 8];
                short8 pf2 = *(const short8*)&Pbuf[wv][pb][1][q16 * 40 + quad * 8];
                short8 vlo = *(const short8*)&Vts[q16        * VSTR + pk * 32 + quad * 8];
                short8 vhi = *(const short8*)&Vts[(16 + q16) * VSTR + pk * 32 + quad * 8];
                __builtin_amdgcn_s_setprio(1);
                o1lo[qbi] = MFMA16(pf1, vlo, o1lo[qbi]);
                o1hi[qbi] = MFMA16(pf1, vhi, o1hi[qbi]);
                o2lo[qbi] = MFMA16(pf2, vlo, o2lo[qbi]);
                o2hi[qbi] = MFMA16(pf2, vhi, o2hi[qbi]);
                accl1[qbi] = MFMA16(pf1, ones8, accl1[qbi]);
                accl2[qbi] = MFMA16(pf2, ones8, accl2[qbi]);
                __builtin_amdgcn_s_setprio(0);
            }
            LDS_FENCE();       // pin: tail reads stay above next qbi's QK writes
        }
    }

    // ---- epilogue: normalize (denominators row-aligned), diff combine,
    //      LayerNorm(32), store ----
    const float g_lo = gamma[q16],      g_hi = gamma[16 + q16];
    const float b_lo = beta[q16],       b_hi = beta[16 + q16];

    #pragma unroll
    for (int qbi = 0; qbi < 2; ++qbi) {
        #pragma unroll
        for (int r = 0; r < 4; ++r) {
            const float i1 = 1.0f / accl1[qbi][r];   // rowsum for q=(lane>>4)*4+r
            const float i2 = 1.0f / accl2[qbi][r];
            const float ylo = o1lo[qbi][r] * i1 - lam * (o2lo[qbi][r] * i2);
            const float yhi = o1hi[qbi][r] * i1 - lam * (o2hi[qbi][r] * i2);

            float s  = ylo + yhi;
            float s2 = ylo * ylo + yhi * yhi;
            #pragma unroll
            for (int off = 1; off < 16; off <<= 1) {
                s  += __shfl_xor(s,  off);
                s2 += __shfl_xor(s2, off);
            }
            const float mu   = s * (1.0f / 32.0f);
            const float var  = s2 * (1.0f / 32.0f) - mu * mu;
            const float rstd = rsqrtf(var + LN_EPS);

            const int row = bt * NTOK + qh * 128 + (qbi * 4 + wv) * 16 + quad * 4 + r;
            float* orow = out + (size_t)row * HID + h * 32;
            orow[q16]      = ((ylo - mu) * rstd * g_lo + b_lo) * ONE_MINUS_LI;
            orow[16 + q16] = ((yhi - mu) * rstd * g_hi + b_hi) * ONE_MINUS_LI;
        }
    }
}

// ---------------------------------------------------------------------------
extern "C" void kernel_launch(void* const* d_in, const int* in_sizes, int n_in,
                              void* d_out, int out_size, void* d_ws, size_t ws_size,
                              hipStream_t stream) {
    const float* x   = (const float*)d_in[0];
    const float* Wq  = (const float*)d_in[1];
    const float* Wk  = (const float*)d_in[2];
    const float* Wv  = (const float*)d_in[3];
    const float* lq1 = (const float*)d_in[4];
    const float* lk1 = (const float*)d_in[5];
    const float* lq2 = (const float*)d_in[6];
    const float* lk2 = (const float*)d_in[7];
    const float* gam = (const float*)d_in[8];
    const float* bet = (const float*)d_in[9];
    float* out = (float*)d_out;

    u16* ws = (u16*)d_ws;
    u16* Wt = ws;                 // 3 * 65536
    u16* Qh = Wt + 3 * 65536;     // head-major [8][16384][32]
    u16* Kh = Qh + TENS;
    u16* Vh = Kh + TENS;

    hipLaunchKernelGGL(prep_w, dim3(4, 4, 3), dim3(256), 0, stream, Wq, Wk, Wv, Wt);
    hipLaunchKernelGGL(proj_kernel, dim3(M_ROWS / 64, HID / 64), dim3(256), 0, stream,
                       x, Wt, Qh, Kh, Vh);
    hipLaunchKernelGGL(attn_kernel, dim3(1024), dim3(256), 0, stream,
                       Qh, Kh, Vh, lq1, lk1, lq2, lk2, gam, bet, out);
}

// Round 17
// 130.428 us; speedup vs baseline: 1.0201x; 1.0064x over previous
//
#include <hip/hip_runtime.h>
#include <cmath>

typedef unsigned short u16;
typedef unsigned int   u32;
typedef __attribute__((ext_vector_type(8))) short short8;
typedef __attribute__((ext_vector_type(4))) float f32x4;

constexpr int BT    = 32;
constexpr int NTOK  = 512;
constexpr int DIM   = 256;
constexpr int HID   = 256;
constexpr int M_ROWS = BT * NTOK;            // 16384
constexpr int HM     = M_ROWS * 32;          // per-head elems in head-major QKV
constexpr size_t TENS = (size_t)M_ROWS * HID; // elems per full tensor
constexpr float LAMBDA_INIT  = 0.35550906759096927f;
constexpr float ONE_MINUS_LI = 0.6444909324090307f;
constexpr float LN_EPS = 1e-5f;
constexpr float QSCALE = 0.36067376022224085f;  // 0.25 * log2(e): fold into Q

// TERMINAL CONFIGURATION (session best, R13: 130.9us, absmax 0.03125).
// Falsification table (16 rounds): occupancy, P-pipelining, staging latency
// (exposed/prefetch/double-buffer), traffic reduction, setprio, store
// coalescing, XCD swizzle -- all neutral/negative on this decomposition.
// Only win: R12 V-stage rebalance (removing idle lanes = wall-clock-serial
// waste). R13's MFMA rowsum denominators kept (time-neutral, best absmax).
// Remaining headroom requires a whole-kernel rewrite (32x32 fragments,
// fused proj+attn) -- out of scope per revert-don't-debug after R9/R11.
constexpr int KCHUNK = 128;

#define MFMA16(a, b, c) __builtin_amdgcn_mfma_f32_16x16x32_bf16((a), (b), (c), 0, 0, 0)
#define LDS_FENCE() asm volatile("" ::: "memory")

__device__ __forceinline__ u16 f2bf(float f) {   // RNE
    u32 u = __float_as_uint(f);
    return (u16)((u + 0x7FFFu + ((u >> 16) & 1u)) >> 16);
}

__device__ __forceinline__ float fexp2(float x) {
#if defined(__has_builtin) && __has_builtin(__builtin_amdgcn_exp2f)
    return __builtin_amdgcn_exp2f(x);
#else
    return exp2f(x);
#endif
}

// pack two f32 -> two bf16 (round-half-up) in one dword: a in low half
__device__ __forceinline__ u32 pack_bf16(float a, float b) {
    u32 ua = __float_as_uint(a) + 0x8000u;
    u32 ub = __float_as_uint(b) + 0x8000u;
    return __builtin_amdgcn_perm(ub, ua, 0x07060302u);
}

// ---------------------------------------------------------------------------
// prep_w: transpose + convert W (f32 [k][n]) -> Wt (bf16 [n][k]), 3 matrices
// ---------------------------------------------------------------------------
__global__ __launch_bounds__(256) void prep_w(const float* __restrict__ Wq,
                                              const float* __restrict__ Wk,
                                              const float* __restrict__ Wv,
                                              u16* __restrict__ Wt) {
    const float* W = (blockIdx.z == 0) ? Wq : (blockIdx.z == 1) ? Wk : Wv;
    u16* dst = Wt + (size_t)blockIdx.z * 65536;
    __shared__ float T[64][65];
    const int k0 = blockIdx.x * 64, n0 = blockIdx.y * 64;
    const int tr = threadIdx.x >> 4;
    const int tc = threadIdx.x & 15;
    #pragma unroll
    for (int i = 0; i < 4; ++i) {
        int row = tr + i * 16;
        float4 v = *(const float4*)&W[(size_t)(k0 + row) * HID + n0 + tc * 4];
        T[row][tc * 4 + 0] = v.x; T[row][tc * 4 + 1] = v.y;
        T[row][tc * 4 + 2] = v.z; T[row][tc * 4 + 3] = v.w;
    }
    __syncthreads();
    #pragma unroll
    for (int i = 0; i < 4; ++i) {
        int n = tr + i * 16;
        int k4 = tc * 4;
        uint2 pk;
        pk.x = (u32)f2bf(T[k4 + 0][n]) | ((u32)f2bf(T[k4 + 1][n]) << 16);
        pk.y = (u32)f2bf(T[k4 + 2][n]) | ((u32)f2bf(T[k4 + 3][n]) << 16);
        *(uint2*)&dst[(size_t)(n0 + n) * DIM + k0 + k4] = pk;
    }
}

// ---------------------------------------------------------------------------
// proj: fused QKV GEMM (R5-proven structure). Stages x tile (f32->bf16
// inline), multiplies by all 3 weights. Tile 64x64, BK=64, 4 waves each
// 32x32. Writes head-major bf16 [h][row][32]; Q scaled by QSCALE.
// ---------------------------------------------------------------------------
__global__ __launch_bounds__(256, 3) void proj_kernel(
    const float* __restrict__ x, const u16* __restrict__ Wt,
    u16* __restrict__ Qh, u16* __restrict__ Kh, u16* __restrict__ Vh)
{
    __shared__ u16 As[64 * 72];      // [m][k], stride 72 (144B, 16B aligned)
    __shared__ u16 Bs[3][64 * 72];   // [n][k] per z

    const int tid  = threadIdx.x;
    const int m0   = blockIdx.x * 64;
    const int n0   = blockIdx.y * 64;
    const int lane = tid & 63;
    const int wv   = tid >> 6;
    const int q16  = lane & 15;
    const int quad = lane >> 4;
    const int mw   = (wv >> 1) * 32;
    const int nw   = (wv & 1) * 32;

    const int sr = tid >> 2;          // 0..63 staging row
    const int sc = (tid & 3) * 16;    // 0,16,32,48 (u16 offset within 64-k)

    f32x4 acc[3][4];
    #pragma unroll
    for (int z = 0; z < 3; ++z)
        #pragma unroll
        for (int t = 0; t < 4; ++t)
            acc[z][t] = (f32x4){0.f, 0.f, 0.f, 0.f};

    for (int kk = 0; kk < DIM; kk += 64) {
        // A tile: load f32, convert to bf16
        {
            const float4* xs = (const float4*)&x[(size_t)(m0 + sr) * DIM + kk + sc];
            float4 g0 = xs[0], g1 = xs[1], g2 = xs[2], g3 = xs[3];
            uint4 o0, o1;
            o0.x = (u32)f2bf(g0.x) | ((u32)f2bf(g0.y) << 16);
            o0.y = (u32)f2bf(g0.z) | ((u32)f2bf(g0.w) << 16);
            o0.z = (u32)f2bf(g1.x) | ((u32)f2bf(g1.y) << 16);
            o0.w = (u32)f2bf(g1.z) | ((u32)f2bf(g1.w) << 16);
            o1.x = (u32)f2bf(g2.x) | ((u32)f2bf(g2.y) << 16);
            o1.y = (u32)f2bf(g2.z) | ((u32)f2bf(g2.w) << 16);
            o1.z = (u32)f2bf(g3.x) | ((u32)f2bf(g3.y) << 16);
            o1.w = (u32)f2bf(g3.z) | ((u32)f2bf(g3.w) << 16);
            *(uint4*)&As[sr * 72 + sc]     = o0;
            *(uint4*)&As[sr * 72 + sc + 8] = o1;
        }
        // B tiles (already bf16 in Wt)
        #pragma unroll
        for (int z = 0; z < 3; ++z) {
            const uint4* ws4 = (const uint4*)&Wt[(size_t)z * 65536 + (size_t)(n0 + sr) * DIM + kk + sc];
            *(uint4*)&Bs[z][sr * 72 + sc]     = ws4[0];
            *(uint4*)&Bs[z][sr * 72 + sc + 8] = ws4[1];
        }
        __syncthreads();
        #pragma unroll
        for (int kc = 0; kc < 2; ++kc) {
            short8 a0 = *(const short8*)&As[(mw +      q16) * 72 + kc * 32 + quad * 8];
            short8 a1 = *(const short8*)&As[(mw + 16 + q16) * 72 + kc * 32 + quad * 8];
            #pragma unroll
            for (int z = 0; z < 3; ++z) {
                short8 b0 = *(const short8*)&Bs[z][(nw +      q16) * 72 + kc * 32 + quad * 8];
                short8 b1 = *(const short8*)&Bs[z][(nw + 16 + q16) * 72 + kc * 32 + quad * 8];
                acc[z][0] = MFMA16(a0, b0, acc[z][0]);
                acc[z][1] = MFMA16(a0, b1, acc[z][1]);
                acc[z][2] = MFMA16(a1, b0, acc[z][2]);
                acc[z][3] = MFMA16(a1, b1, acc[z][3]);
            }
        }
        __syncthreads();
    }

    // epilogue: head-major store. C/D: col=lane&15, row=quad*4+reg
    const int hcol = (n0 + nw) >> 5;     // (n0+nw) is a multiple of 32
    #pragma unroll
    for (int z = 0; z < 3; ++z) {
        u16* C = (z == 0) ? Qh : (z == 1) ? Kh : Vh;
        u16* base = C + (size_t)hcol * HM;
        const float s = (z == 0) ? QSCALE : 1.0f;
        #pragma unroll
        for (int r = 0; r < 4; ++r) {
            const int row = m0 + mw + quad * 4 + r;
            base[(size_t)row * 32 + q16]             = f2bf(acc[z][0][r] * s);
            base[(size_t)row * 32 + q16 + 16]        = f2bf(acc[z][1][r] * s);
            base[(size_t)(row + 16) * 32 + q16]      = f2bf(acc[z][2][r] * s);
            base[(size_t)(row + 16) * 32 + q16 + 16] = f2bf(acc[z][3][r] * s);
        }
    }
}

// ---------------------------------------------------------------------------
// attn: transposed-QK MFMA attention + diff combine + LayerNorm.
// R13 exact (session best): KCHUNK=128 single-buffer, 256-thread V-stage
// (R12), MFMA rowsum denominators (R13), setprio around MFMA clusters,
// parity-double-buffered P with LDS_FENCE ordering (R4/R5).
// ---------------------------------------------------------------------------
__global__ __launch_bounds__(256, 3) void attn_kernel(
    const u16* __restrict__ Qh, const u16* __restrict__ Kh, const u16* __restrict__ Vh,
    const float* __restrict__ lq1, const float* __restrict__ lk1,
    const float* __restrict__ lq2, const float* __restrict__ lk2,
    const float* __restrict__ gamma, const float* __restrict__ beta,
    float* __restrict__ out)
{
    constexpr int VSTR = KCHUNK + 8;
    constexpr int NKC  = KCHUNK / 32;        // 4 kc steps per chunk

    __shared__ u16 Ks[KCHUNK * 40];          // [key][dim] 10.0KB
    __shared__ u16 Vts[32 * VSTR];           // [dim][key]  8.5KB
    __shared__ u16 Pbuf[4][2][2][16 * 40];   // [wave][parity][matrix][q][key] 20.5KB

    const int qh  = blockIdx.x;   // 0..3 (128 q rows each)
    const int h   = blockIdx.y;   // 0..7
    const int bt  = blockIdx.z;   // 0..31
    const int tid = threadIdx.x;
    const int lane = tid & 63;
    const int wv   = tid >> 6;
    const int q16  = lane & 15;
    const int quad = lane >> 4;

    // lambda scalar (uniform path)
    float sa = 0.f, sb = 0.f;
    #pragma unroll
    for (int d = 0; d < 16; ++d) { sa += lq1[d] * lk1[d]; sb += lq2[d] * lk2[d]; }
    const float lam = __expf(sa) - __expf(sb) + LAMBDA_INIT;

    // Q B-fragments for this wave's two 16-row q blocks (pre-scaled at proj)
    short8 qv[2];
    #pragma unroll
    for (int qbi = 0; qbi < 2; ++qbi) {
        const int qrow = bt * NTOK + qh * 128 + (qbi * 4 + wv) * 16 + q16;
        qv[qbi] = *(const short8*)(Qh + (size_t)h * HM + (size_t)qrow * 32 + quad * 8);
    }

    const short8 z8 = {0, 0, 0, 0, 0, 0, 0, 0};
    const f32x4  z4 = {0.f, 0.f, 0.f, 0.f};
    const short8 ones8 = {(short)0x3F80, (short)0x3F80, (short)0x3F80, (short)0x3F80,
                          (short)0x3F80, (short)0x3F80, (short)0x3F80, (short)0x3F80};

    f32x4 o1lo[2], o1hi[2], o2lo[2], o2hi[2];
    f32x4 accl1[2], accl2[2];            // rowsum accumulators (denominators)
    #pragma unroll
    for (int qbi = 0; qbi < 2; ++qbi) {
        o1lo[qbi] = z4; o1hi[qbi] = z4; o2lo[qbi] = z4; o2hi[qbi] = z4;
        accl1[qbi] = z4; accl2[qbi] = z4;
    }

    for (int chunk = 0; chunk < NTOK / KCHUNK; ++chunk) {
        if (chunk) __syncthreads();   // drain previous chunk's LDS reads
        // ---- stage K chunk: 128 rows, 2 threads per row (32B each, coalesced) ----
        {
            const int key  = tid >> 1;
            const int half = (tid & 1) * 16;   // u16 offset within 32-dim row
            const uint4* src = (const uint4*)(Kh + (size_t)h * HM +
                                (size_t)(bt * NTOK + chunk * KCHUNK + key) * 32 + half);
            uint4* dst = (uint4*)&Ks[key * 40 + half];
            dst[0] = src[0]; dst[1] = src[1];
        }
        // ---- stage V chunk transposed: ALL 256 threads (R12 rebalance) ----
        {
            const int pr = tid >> 2;          // key pair 0..63
            const int qd = tid & 3;           // dword quarter 0..3
            const int j0 = pr * 2;
            const u16* v0 = Vh + (size_t)h * HM + (size_t)(bt * NTOK + chunk * KCHUNK + j0) * 32;
            union U { uint4 q4; u32 w[4]; } ra, rb;
            ra.q4 = ((const uint4*)v0)[qd];        // key j0,  dims 8qd..8qd+7
            rb.q4 = ((const uint4*)(v0 + 32))[qd]; // key j0+1, same dims
            #pragma unroll
            for (int k = 0; k < 4; ++k) {
                const int w = qd * 4 + k;          // dword index 0..15 (dims 2w,2w+1)
                u32 lo = __builtin_amdgcn_perm(rb.w[k], ra.w[k], 0x05040100u); // dim 2w
                u32 hi = __builtin_amdgcn_perm(rb.w[k], ra.w[k], 0x07060302u); // dim 2w+1
                *(u32*)&Vts[(2 * w)     * VSTR + j0] = lo;
                *(u32*)&Vts[(2 * w + 1) * VSTR + j0] = hi;
            }
        }
        __syncthreads();

        #pragma unroll
        for (int qbi = 0; qbi < 2; ++qbi) {
            const short8 A1 = (lane < 32) ? qv[qbi] : z8;  // dims 0..15
            const short8 A2 = (lane < 32) ? z8 : qv[qbi];  // dims 16..31

            #pragma unroll
            for (int kc = 0; kc < NKC; ++kc) {
                // ---- QK phase for step kc -> Pbuf[wv][kc&1] ----
                #pragma unroll
                for (int sub = 0; sub < 2; ++sub) {
                    const int key0 = kc * 32 + sub * 16;
                    short8 kf = *(const short8*)&Ks[(key0 + q16) * 40 + quad * 8];
                    // S^T: D[key=quad*4+r][q=q16]
                    __builtin_amdgcn_s_setprio(1);
                    f32x4 s1 = MFMA16(kf, A1, z4);
                    f32x4 s2 = MFMA16(kf, A2, z4);
                    __builtin_amdgcn_s_setprio(0);
                    float p0 = fexp2(s1[0]), p1 = fexp2(s1[1]);
                    float p2 = fexp2(s1[2]), p3 = fexp2(s1[3]);
                    uint2 w1; w1.x = pack_bf16(p0, p1); w1.y = pack_bf16(p2, p3);
                    *(uint2*)&Pbuf[wv][kc & 1][0][q16 * 40 + sub * 16 + quad * 4] = w1;
                    float r0 = fexp2(s2[0]), r1 = fexp2(s2[1]);
                    float r2 = fexp2(s2[2]), r3 = fexp2(s2[3]);
                    uint2 w2; w2.x = pack_bf16(r0, r1); w2.y = pack_bf16(r2, r3);
                    *(uint2*)&Pbuf[wv][kc & 1][1][q16 * 40 + sub * 16 + quad * 4] = w2;
                }
                LDS_FENCE();   // pin: QK writes of kc stay above PV reads below
                // ---- PV phase for step kc-1 <- Pbuf[wv][(kc-1)&1] ----
                if (kc > 0) {
                    const int pk = kc - 1;
                    const int pb = (kc - 1) & 1;
                    short8 pf1 = *(const short8*)&Pbuf[wv][pb][0][q16 * 40 + quad * 8];
                    short8 pf2 = *(const short8*)&Pbuf[wv][pb][1][q16 * 40 + quad * 8];
                    short8 vlo = *(const short8*)&Vts[q16        * VSTR + pk * 32 + quad * 8];
                    short8 vhi = *(const short8*)&Vts[(16 + q16) * VSTR + pk * 32 + quad * 8];
                    __builtin_amdgcn_s_setprio(1);
                    o1lo[qbi] = MFMA16(pf1, vlo, o1lo[qbi]);
                    o1hi[qbi] = MFMA16(pf1, vhi, o1hi[qbi]);
                    o2lo[qbi] = MFMA16(pf2, vlo, o2lo[qbi]);
                    o2hi[qbi] = MFMA16(pf2, vhi, o2hi[qbi]);
                    accl1[qbi] = MFMA16(pf1, ones8, accl1[qbi]);
                    accl2[qbi] = MFMA16(pf2, ones8, accl2[qbi]);
                    __builtin_amdgcn_s_setprio(0);
                }
                LDS_FENCE();   // pin: PV reads of kc-1 stay above QK writes of kc+1
            }
            // ---- PV tail for step NKC-1 ----
            {
                const int pk = NKC - 1;
                const int pb = (NKC - 1) & 1;
                short8 pf1 = *(const short8*)&Pbuf[wv][pb][0][q16 * 40 + quad * 8];
                short8 pf2 = *(const short8*)&Pbuf[wv][pb][1][q16 * 40 + quad * 8];
                short8 vlo = *(const short8*)&Vts[q16        * VSTR + pk * 32 + quad * 8];
                short8 vhi = *(const short8*)&Vts[(16 + q16) * VSTR + pk * 32 + quad * 8];
                __builtin_amdgcn_s_setprio(1);
                o1lo[qbi] = MFMA16(pf1, vlo, o1lo[qbi]);
                o1hi[qbi] = MFMA16(pf1, vhi, o1hi[qbi]);
                o2lo[qbi] = MFMA16(pf2, vlo, o2lo[qbi]);
                o2hi[qbi] = MFMA16(pf2, vhi, o2hi[qbi]);
                accl1[qbi] = MFMA16(pf1, ones8, accl1[qbi]);
                accl2[qbi] = MFMA16(pf2, ones8, accl2[qbi]);
                __builtin_amdgcn_s_setprio(0);
            }
            LDS_FENCE();       // pin: tail reads stay above next qbi's QK writes
        }
    }

    // ---- epilogue: normalize (denominators row-aligned), diff combine,
    //      LayerNorm(32), store ----
    const float g_lo = gamma[q16],      g_hi = gamma[16 + q16];
    const float b_lo = beta[q16],       b_hi = beta[16 + q16];

    #pragma unroll
    for (int qbi = 0; qbi < 2; ++qbi) {
        #pragma unroll
        for (int r = 0; r < 4; ++r) {
            const float i1 = 1.0f / accl1[qbi][r];   // rowsum for q=(lane>>4)*4+r
            const float i2 = 1.0f / accl2[qbi][r];
            const float ylo = o1lo[qbi][r] * i1 - lam * (o2lo[qbi][r] * i2);
            const float yhi = o1hi[qbi][r] * i1 - lam * (o2hi[qbi][r] * i2);

            float s  = ylo + yhi;
            float s2 = ylo * ylo + yhi * yhi;
            #pragma unroll
            for (int off = 1; off < 16; off <<= 1) {
                s  += __shfl_xor(s,  off);
                s2 += __shfl_xor(s2, off);
            }
            const float mu   = s * (1.0f / 32.0f);
            const float var  = s2 * (1.0f / 32.0f) - mu * mu;
            const float rstd = rsqrtf(var + LN_EPS);

            const int row = bt * NTOK + qh * 128 + (qbi * 4 + wv) * 16 + quad * 4 + r;
            float* orow = out + (size_t)row * HID + h * 32;
            orow[q16]      = ((ylo - mu) * rstd * g_lo + b_lo) * ONE_MINUS_LI;
            orow[16 + q16] = ((yhi - mu) * rstd * g_hi + b_hi) * ONE_MINUS_LI;
        }
    }
}

// ---------------------------------------------------------------------------
extern "C" void kernel_launch(void* const* d_in, const int* in_sizes, int n_in,
                              void* d_out, int out_size, void* d_ws, size_t ws_size,
                              hipStream_t stream) {
    const float* x   = (const float*)d_in[0];
    const float* Wq  = (const float*)d_in[1];
    const float* Wk  = (const float*)d_in[2];
    const float* Wv  = (const float*)d_in[3];
    const float* lq1 = (const float*)d_in[4];
    const float* lk1 = (const float*)d_in[5];
    const float* lq2 = (const float*)d_in[6];
    const float* lk2 = (const float*)d_in[7];
    const float* gam = (const float*)d_in[8];
    const float* bet = (const float*)d_in[9];
    float* out = (float*)d_out;

    u16* ws = (u16*)d_ws;
    u16* Wt = ws;                 // 3 * 65536
    u16* Qh = Wt + 3 * 65536;     // head-major [8][16384][32]
    u16* Kh = Qh + TENS;
    u16* Vh = Kh + TENS;

    hipLaunchKernelGGL(prep_w, dim3(4, 4, 3), dim3(256), 0, stream, Wq, Wk, Wv, Wt);
    hipLaunchKernelGGL(proj_kernel, dim3(M_ROWS / 64, HID / 64), dim3(256), 0, stream,
                       x, Wt, Qh, Kh, Vh);
    hipLaunchKernelGGL(attn_kernel, dim3(4, 8, 32), dim3(256), 0, stream,
                       Qh, Kh, Vh, lq1, lk1, lq2, lk2, gam, bet, out);
}